// Round 16
// baseline (548.477 us; speedup 1.0000x reference)
//
#include <hip/hip_runtime.h>

#define CIN  64
#define COUT 64
#define KVOL 27
#define CAP  (KVOL * 128)          // universal per-block entry bound (3456)
#define ASTRIDE 68                 // LDS acc row stride in floats

typedef __attribute__((ext_vector_type(8))) short bf16x8;
typedef __attribute__((ext_vector_type(4))) float f32x4;

union U4H8 { uint4 u; bf16x8 h; };

static __device__ __forceinline__ unsigned short f2bf(float x) {
    union { float f; unsigned int u; } v; v.f = x;
    return (unsigned short)((v.u + 0x7FFFu + ((v.u >> 16) & 1u)) >> 16);  // RNE
}

// Re-pack weight[27][64][64] fp32 -> bf16 B-fragment order:
// entry e = (k*8 + kh*4 + ntl)*64 + lane holds 8 bf16 =
//   W[k][32*kh + (lane>>4)*8 + j][16*ntl + (lane&15)]
__global__ __launch_bounds__(256) void pack_w(const float* __restrict__ W,
                                              unsigned short* __restrict__ wf) {
    int t = blockIdx.x * 256 + threadIdx.x;
    if (t >= KVOL * 8 * 64) return;
    int lane  = t & 63;
    int frag  = (t >> 6) & 7;
    int k     = t >> 9;
    int kh    = frag >> 2, nt = frag & 3;
    int col   = nt * 16 + (lane & 15);
    int kbase = kh * 32 + (lane >> 4) * 8;
    const float* src = W + (size_t)k * (CIN * COUT) + (size_t)kbase * COUT + col;
    unsigned int pk[4];
    #pragma unroll
    for (int j = 0; j < 4; ++j) {
        unsigned int lo = f2bf(src[(2 * j) * COUT]);
        unsigned int hi = f2bf(src[(2 * j + 1) * COUT]);
        pk[j] = lo | (hi << 16);
    }
    *reinterpret_cast<uint4*>(wf + (size_t)t * 8) = make_uint4(pk[0], pk[1], pk[2], pk[3]);
}

// feats fp32 [N][64] -> bf16 [N+1][64] (row N = zeros). One thread = 8 elems.
__global__ __launch_bounds__(256) void cvt_feats(const float* __restrict__ f,
                                                 uint4* __restrict__ o, int total8) {
    int t = blockIdx.x * 256 + threadIdx.x;
    if (t < total8) {
        const float4* p = reinterpret_cast<const float4*>(f) + 2 * (size_t)t;
        float4 a = p[0], b = p[1];
        unsigned int u0 = (unsigned int)f2bf(a.x) | ((unsigned int)f2bf(a.y) << 16);
        unsigned int u1 = (unsigned int)f2bf(a.z) | ((unsigned int)f2bf(a.w) << 16);
        unsigned int u2 = (unsigned int)f2bf(b.x) | ((unsigned int)f2bf(b.y) << 16);
        unsigned int u3 = (unsigned int)f2bf(b.z) | ((unsigned int)f2bf(b.w) << 16);
        o[t] = make_uint4(u0, u1, u2, u3);
    } else if (t < total8 + 8) {
        o[t] = make_uint4(0u, 0u, 0u, 0u);   // zero row at index N
    }
}

// Prep: per 128-row block, compact valid (k,row) pairs into per-k tiles of 16.
// Entry encoding: bits[0:19)=in_idx (n for zero row), [19:26)=row_local,
// [26:31)=k. Each k's segment padded to x16. PADS carry row_local = tid so
// their (zero) scatter-adds spread across rows -- no same-address convoy.
__global__ __launch_bounds__(128) void pack_pairs(
    const int*   __restrict__ in_idx,
    const float* __restrict__ mask,
    unsigned*    __restrict__ entries,
    int*         __restrict__ ntiles, int n)
{
    const int tid  = threadIdx.x;
    const int lane = tid & 63;
    const int wv   = tid >> 6;
    const int bid  = blockIdx.x;
    const int row  = bid * 128 + tid;

    __shared__ int cnt;
    __shared__ int wc[2];
    if (tid == 0) cnt = 0;

    unsigned* eb = entries + (size_t)bid * CAP;

    for (int k = 0; k < KVOL; ++k) {
        __syncthreads();                              // cnt stable, wc reusable
        const bool v = mask[(size_t)k * n + row] != 0.0f;
        const int  gi = v ? in_idx[(size_t)k * n + row] : 0;
        unsigned long long b = __ballot(v);
        int within = (int)__popcll(b & ((1ull << lane) - 1ull));
        if (lane == 0) wc[wv] = (int)__popcll(b);
        __syncthreads();
        const int base = cnt;
        const int pos  = within + (wv ? wc[0] : 0);
        const int c    = wc[0] + wc[1];
        const int cp   = (c + 15) & ~15;
        if (v) eb[base + pos] = (unsigned)gi | ((unsigned)tid << 19) | ((unsigned)k << 26);
        if (tid >= c && tid < cp)
            eb[base + tid] = (unsigned)n | ((unsigned)tid << 19) | ((unsigned)k << 26);
        __syncthreads();
        if (tid == 0) cnt = base + cp;
    }
    __syncthreads();
    if (tid == 0) ntiles[bid] = cnt / 16;
}

// Main: 8 free-running waves per 128-row block, no barriers in the hot loop.
// 2-deep pipeline: entries for t+16 and gathers for t+8 issued before the
// compute of t. Gathers ONLY valid rows (~5x less than dense). 8 MFMAs into
// transient acc, scatter-add into LDS fp32 accumulator (distinct pad rows).
__global__ __launch_bounds__(512) void spconv_compact(
    const char* __restrict__ fbf,          // (n+1) rows x 128 B bf16
    const uint4* __restrict__ wf4,
    const float* __restrict__ bias,
    const unsigned* __restrict__ entries,
    const int* __restrict__ ntiles,
    float* __restrict__ out, int n)
{
    const int tid  = threadIdx.x;
    const int lane = tid & 63;
    const int wv   = tid >> 6;
    const int rloc = lane & 15;
    const int grp  = lane >> 4;
    const int bid  = blockIdx.x;
    const int row0 = bid * 128;

    __shared__ float accs[128 * ASTRIDE];   // 34.8 KB

    // init to bias
    for (int j = tid; j < 128 * 64; j += 512) {
        int r = j >> 6, c = j & 63;
        accs[r * ASTRIDE + c] = bias[c];
    }
    __syncthreads();

    const int nt = ntiles[bid];
    const unsigned* eb = entries + (size_t)bid * CAP;

    int t = wv;
    unsigned evA = 0, evB = 0;
    U4H8 aA0, aA1;
    if (t < nt) {
        evA = eb[t * 16 + rloc];
        const char* src = fbf + (size_t)(evA & 0x7FFFFu) * 128 + grp * 16;
        aA0.u = *reinterpret_cast<const uint4*>(src);
        aA1.u = *reinterpret_cast<const uint4*>(src + 64);
    }
    if (t + 8 < nt) evB = eb[(t + 8) * 16 + rloc];

    for (; t < nt; t += 8) {
        // stage t+8 gathers (from entries loaded last iter) + t+16 entries
        U4H8 nA0, nA1;
        const bool nx = (t + 8) < nt;
        if (nx) {
            const char* src = fbf + (size_t)(evB & 0x7FFFFu) * 128 + grp * 16;
            nA0.u = *reinterpret_cast<const uint4*>(src);
            nA1.u = *reinterpret_cast<const uint4*>(src + 64);
        }
        unsigned evC = 0;
        if (t + 16 < nt) evC = eb[(t + 16) * 16 + rloc];
        __builtin_amdgcn_sched_barrier(0);

        // compute tile t
        const int k  = __builtin_amdgcn_readfirstlane((int)(evA >> 26));
        const int rl = (int)((evA >> 19) & 127u);
        const uint4* wk = wf4 + (size_t)k * 512 + lane;
        f32x4 acc[4];
        #pragma unroll
        for (int ntl = 0; ntl < 4; ++ntl) {
            U4H8 b0, b1;
            b0.u = wk[ntl * 64];                      // kh = 0
            b1.u = wk[(4 + ntl) * 64];                // kh = 1
            f32x4 z = {0.f, 0.f, 0.f, 0.f};
            acc[ntl] = __builtin_amdgcn_mfma_f32_16x16x32_bf16(aA0.h, b0.h, z, 0, 0, 0);
            acc[ntl] = __builtin_amdgcn_mfma_f32_16x16x32_bf16(aA1.h, b1.h, acc[ntl], 0, 0, 0);
        }

        // C: col = ntl*16 + rloc, tile-row = grp*4 + r -> scatter to LDS
        #pragma unroll
        for (int r = 0; r < 4; ++r) {
            const int rlr = __shfl(rl, grp * 4 + r, 16);
            #pragma unroll
            for (int ntl = 0; ntl < 4; ++ntl)
                atomicAdd(&accs[rlr * ASTRIDE + ntl * 16 + rloc], acc[ntl][r]);
        }

        evA = evB; evB = evC; aA0 = nA0; aA1 = nA1;
    }
    __syncthreads();

    // coalesced float4 writeout
    float4* o4 = reinterpret_cast<float4*>(out + (size_t)row0 * 64);
    for (int j = tid; j < 128 * 16; j += 512) {
        int r = j >> 4, c4 = (j & 15) * 4;
        const float* s = &accs[r * ASTRIDE + c4];
        o4[j] = make_float4(s[0], s[1], s[2], s[3]);
    }
}

// ---- mid fallback: round-9 kernel (87 us) if ws fits fbf but not entries ----
__global__ __launch_bounds__(256) void spconv_mfma64(
    const char* __restrict__ fbf, const uint4* __restrict__ wf4,
    const float* __restrict__ bias, const int* __restrict__ in_idx,
    const float* __restrict__ mask, float* __restrict__ out, int n)
{
    const int tid  = threadIdx.x;
    const int lane = tid & 63;
    const int wv   = tid >> 6;
    const int rloc = lane & 15;
    const int grp  = lane >> 4;
    const int nwg = gridDim.x;
    int bid = blockIdx.x;
    if ((nwg & 7) == 0) {
        const int chunk = nwg >> 3;
        bid = (blockIdx.x & 7) * chunk + (blockIdx.x >> 3);
    }
    const int row0 = bid * 256 + wv * 64;

    __shared__ uint4 lds_w[2][512];
    f32x4 acc[4][4];
    #pragma unroll
    for (int nt = 0; nt < 4; ++nt) {
        float b = bias[nt * 16 + rloc];
        f32x4 v = {b, b, b, b};
        acc[0][nt] = v; acc[1][nt] = v; acc[2][nt] = v; acc[3][nt] = v;
    }
    int rowt[4];
    #pragma unroll
    for (int t = 0; t < 4; ++t) rowt[t] = row0 + 16 * t + rloc;
    const unsigned zoff = (unsigned)n * 128u;

    lds_w[0][tid]       = wf4[tid];
    lds_w[0][tid + 256] = wf4[tid + 256];
    __syncthreads();

    U4H8 a[3][4][2];
    {
        int i0[4]; float m0[4];
        #pragma unroll
        for (int t = 0; t < 4; ++t) { i0[t] = in_idx[rowt[t]]; m0[t] = mask[rowt[t]]; }
        #pragma unroll
        for (int t = 0; t < 4; ++t) {
            unsigned o = (m0[t] != 0.0f) ? (unsigned)i0[t] * 128u : zoff;
            const uint4* p = reinterpret_cast<const uint4*>(fbf + o) + grp;
            a[0][t][0].u = p[0]; a[0][t][1].u = p[4];
        }
        #pragma unroll
        for (int t = 0; t < 4; ++t) { i0[t] = in_idx[(size_t)n + rowt[t]]; m0[t] = mask[(size_t)n + rowt[t]]; }
        #pragma unroll
        for (int t = 0; t < 4; ++t) {
            unsigned o = (m0[t] != 0.0f) ? (unsigned)i0[t] * 128u : zoff;
            const uint4* p = reinterpret_cast<const uint4*>(fbf + o) + grp;
            a[1][t][0].u = p[0]; a[1][t][1].u = p[4];
        }
    }
    int idxb[2][4]; float mskb[2][4];
    #pragma unroll
    for (int t = 0; t < 4; ++t) { idxb[0][t] = in_idx[(size_t)2*n + rowt[t]]; mskb[0][t] = mask[(size_t)2*n + rowt[t]]; }
    #pragma unroll
    for (int t = 0; t < 4; ++t) { idxb[1][t] = in_idx[(size_t)3*n + rowt[t]]; mskb[1][t] = mask[(size_t)3*n + rowt[t]]; }

    #pragma unroll
    for (int k = 0; k < KVOL; ++k) {
        const int cur = k & 1, nxt = cur ^ 1;
        const int cslot = k % 3, gslot = (k + 2) % 3, islot = k & 1;
        uint4 w0, w1;
        if (k + 1 < KVOL) {
            const uint4* s = wf4 + (size_t)(k + 1) * 512;
            w0 = s[tid]; w1 = s[tid + 256];
        }
        if (k + 2 < KVOL) {
            #pragma unroll
            for (int t = 0; t < 4; ++t) {
                unsigned o = (mskb[islot][t] != 0.0f) ? (unsigned)idxb[islot][t] * 128u : zoff;
                const uint4* p = reinterpret_cast<const uint4*>(fbf + o) + grp;
                a[gslot][t][0].u = p[0]; a[gslot][t][1].u = p[4];
            }
        }
        if (k + 4 < KVOL) {
            const size_t kb = (size_t)(k + 4) * n;
            #pragma unroll
            for (int t = 0; t < 4; ++t) { idxb[islot][t] = in_idx[kb + rowt[t]]; mskb[islot][t] = mask[kb + rowt[t]]; }
        }
        __builtin_amdgcn_sched_barrier(0);
        U4H8 bf[2][4];
        #pragma unroll
        for (int kh = 0; kh < 2; ++kh)
            #pragma unroll
            for (int ntl = 0; ntl < 4; ++ntl)
                bf[kh][ntl].u = lds_w[cur][(kh * 4 + ntl) * 64 + lane];
        #pragma unroll
        for (int t = 0; t < 4; ++t)
            #pragma unroll
            for (int ntl = 0; ntl < 4; ++ntl) {
                acc[t][ntl] = __builtin_amdgcn_mfma_f32_16x16x32_bf16(a[cslot][t][0].h, bf[0][ntl].h, acc[t][ntl], 0, 0, 0);
                acc[t][ntl] = __builtin_amdgcn_mfma_f32_16x16x32_bf16(a[cslot][t][1].h, bf[1][ntl].h, acc[t][ntl], 0, 0, 0);
            }
        if (k + 1 < KVOL) {
            lds_w[nxt][tid] = w0; lds_w[nxt][tid + 256] = w1;
            asm volatile("s_waitcnt lgkmcnt(0)" ::: "memory");
            __builtin_amdgcn_s_barrier();
        }
    }
    #pragma unroll
    for (int t = 0; t < 4; ++t)
        #pragma unroll
        for (int ntl = 0; ntl < 4; ++ntl)
            #pragma unroll
            for (int r = 0; r < 4; ++r) {
                int orow = row0 + 16 * t + grp * 4 + r;
                out[(size_t)orow * COUT + ntl * 16 + rloc] = acc[t][ntl][r];
            }
}

// ---- last fallback (round-2 kernel): fp32 gather + in-loop cvt ----
static __device__ __forceinline__ bf16x8 cvt8(float4 a, float4 b, float m) {
    bf16x8 r;
    r[0] = (short)f2bf(a.x * m); r[1] = (short)f2bf(a.y * m);
    r[2] = (short)f2bf(a.z * m); r[3] = (short)f2bf(a.w * m);
    r[4] = (short)f2bf(b.x * m); r[5] = (short)f2bf(b.y * m);
    r[6] = (short)f2bf(b.z * m); r[7] = (short)f2bf(b.w * m);
    return r;
}

__global__ __launch_bounds__(256) void spconv_mfma_f32(
    const float* __restrict__ feats, const unsigned short* __restrict__ wf,
    const float* __restrict__ bias, const int* __restrict__ in_idx,
    const float* __restrict__ mask, float* __restrict__ out, int n)
{
    const int tid  = threadIdx.x;
    const int lane = tid & 63;
    const int wv   = tid >> 6;
    const int rloc = lane & 15;
    const int grp  = lane >> 4;
    const int row0 = blockIdx.x * 128 + wv * 32;

    __shared__ uint4 lds_w[2][512];
    f32x4 acc[2][4];
    #pragma unroll
    for (int nt = 0; nt < 4; ++nt) {
        float b = bias[nt * 16 + rloc];
        f32x4 v = {b, b, b, b};
        acc[0][nt] = v; acc[1][nt] = v;
    }
    const uint4* wf4 = reinterpret_cast<const uint4*>(wf);
    lds_w[0][tid] = wf4[tid];
    lds_w[0][tid + 256] = wf4[tid + 256];
    __syncthreads();
    const int rowA = row0 + rloc, rowB = rowA + 16;
    for (int koff = 0; koff < KVOL; ++koff) {
        const int cur = koff & 1;
        uint4 w0, w1;
        const bool pf = (koff + 1 < KVOL);
        if (pf) {
            const uint4* s = wf4 + (size_t)(koff + 1) * 512;
            w0 = s[tid]; w1 = s[tid + 256];
        }
        const size_t kb = (size_t)koff * n;
        const int idxA = in_idx[kb + rowA]; const float mA = mask[kb + rowA];
        const int idxB = in_idx[kb + rowB]; const float mB = mask[kb + rowB];
        const float4* fA = reinterpret_cast<const float4*>(feats + (size_t)idxA * CIN + grp * 8);
        const float4* fB = reinterpret_cast<const float4*>(feats + (size_t)idxB * CIN + grp * 8);
        float4 a0 = fA[0], a1 = fA[1], a2 = fA[8], a3 = fA[9];
        float4 c0 = fB[0], c1 = fB[1], c2 = fB[8], c3 = fB[9];
        bf16x8 aA0 = cvt8(a0, a1, mA), aA1 = cvt8(a2, a3, mA);
        bf16x8 aB0 = cvt8(c0, c1, mB), aB1 = cvt8(c2, c3, mB);
        U4H8 bf[2][4];
        #pragma unroll
        for (int kh = 0; kh < 2; ++kh)
            #pragma unroll
            for (int nt = 0; nt < 4; ++nt)
                bf[kh][nt].u = lds_w[cur][(kh * 4 + nt) * 64 + lane];
        #pragma unroll
        for (int nt = 0; nt < 4; ++nt) {
            acc[0][nt] = __builtin_amdgcn_mfma_f32_16x16x32_bf16(aA0, bf[0][nt].h, acc[0][nt], 0, 0, 0);
            acc[0][nt] = __builtin_amdgcn_mfma_f32_16x16x32_bf16(aA1, bf[1][nt].h, acc[0][nt], 0, 0, 0);
            acc[1][nt] = __builtin_amdgcn_mfma_f32_16x16x32_bf16(aB0, bf[0][nt].h, acc[1][nt], 0, 0, 0);
            acc[1][nt] = __builtin_amdgcn_mfma_f32_16x16x32_bf16(aB1, bf[1][nt].h, acc[1][nt], 0, 0, 0);
        }
        if (pf) {
            lds_w[cur ^ 1][tid] = w0;
            lds_w[cur ^ 1][tid + 256] = w1;
        }
        __syncthreads();
    }
    #pragma unroll
    for (int t = 0; t < 2; ++t)
        #pragma unroll
        for (int nt = 0; nt < 4; ++nt)
            #pragma unroll
            for (int r = 0; r < 4; ++r) {
                int orow = row0 + t * 16 + grp * 4 + r;
                out[(size_t)orow * COUT + nt * 16 + rloc] = acc[t][nt][r];
            }
}

extern "C" void kernel_launch(void* const* d_in, const int* in_sizes, int n_in,
                              void* d_out, int out_size, void* d_ws, size_t ws_size,
                              hipStream_t stream)
{
    const float* feats  = (const float*)d_in[0];
    const float* weight = (const float*)d_in[1];
    const float* bias   = (const float*)d_in[2];
    const int*   in_idx = (const int*)  d_in[3];
    // d_in[4] = out_idx (unused: out_idx[k][i] == i where mask==1)
    const float* mask   = (const float*)d_in[5];
    float* out = (float*)d_out;

    const int n = in_sizes[0] / CIN;  // 262144
    const int nblk = n / 128;         // 2048

    const size_t WF_BYTES  = (size_t)KVOL * 8 * 64 * 16;          // 221184
    const size_t FBF_BYTES = (size_t)(n + 1) * CIN * 2;           // ~33.6 MB
    const size_t ENT_BYTES = (size_t)nblk * CAP * 4;              // ~28.3 MB
    const size_t NT_BYTES  = (size_t)nblk * 4;

    unsigned short* wf = (unsigned short*)d_ws;
    const int packN = KVOL * 8 * 64;
    pack_w<<<(packN + 255) / 256, 256, 0, stream>>>(weight, wf);

    if (ws_size >= WF_BYTES + FBF_BYTES + ENT_BYTES + NT_BYTES) {
        char*     fbf = (char*)d_ws + WF_BYTES;
        unsigned* ent = (unsigned*)(fbf + FBF_BYTES);
        int*      ntl = (int*)((char*)ent + ENT_BYTES);
        const int total8 = n * 8;
        cvt_feats<<<(total8 + 8 + 255) / 256, 256, 0, stream>>>(feats, (uint4*)fbf, total8);
        pack_pairs<<<nblk, 128, 0, stream>>>(in_idx, mask, ent, ntl, n);
        spconv_compact<<<nblk, 512, 0, stream>>>(fbf, (const uint4*)wf, bias,
                                                 ent, ntl, out, n);
    } else if (ws_size >= WF_BYTES + FBF_BYTES) {
        char* fbf = (char*)d_ws + WF_BYTES;
        const int total8 = n * 8;
        cvt_feats<<<(total8 + 8 + 255) / 256, 256, 0, stream>>>(feats, (uint4*)fbf, total8);
        spconv_mfma64<<<n / 256, 256, 0, stream>>>(fbf, (const uint4*)wf, bias,
                                                   in_idx, mask, out, n);
    } else {
        spconv_mfma_f32<<<n / 128, 256, 0, stream>>>(feats, wf, bias,
                                                     in_idx, mask, out, n);
    }
}

// Round 17
// 89.058 us; speedup vs baseline: 6.1587x; 6.1587x over previous
//
#include <hip/hip_runtime.h>

#define CIN  64
#define COUT 64
#define KVOL 27

typedef __attribute__((ext_vector_type(8))) short bf16x8;
typedef __attribute__((ext_vector_type(4))) float f32x4;

union U4H8 { uint4 u; bf16x8 h; };

static __device__ __forceinline__ unsigned short f2bf(float x) {
    union { float f; unsigned int u; } v; v.f = x;
    return (unsigned short)((v.u + 0x7FFFu + ((v.u >> 16) & 1u)) >> 16);  // RNE
}

// Re-pack weight[27][64][64] fp32 -> bf16 B-fragment order:
// entry e = (k*8 + kh*4 + ntl)*64 + lane holds 8 bf16 =
//   W[k][32*kh + (lane>>4)*8 + j][16*ntl + (lane&15)]
__global__ __launch_bounds__(256) void pack_w(const float* __restrict__ W,
                                              unsigned short* __restrict__ wf) {
    int t = blockIdx.x * 256 + threadIdx.x;
    if (t >= KVOL * 8 * 64) return;
    int lane  = t & 63;
    int frag  = (t >> 6) & 7;
    int k     = t >> 9;
    int kh    = frag >> 2, nt = frag & 3;
    int col   = nt * 16 + (lane & 15);
    int kbase = kh * 32 + (lane >> 4) * 8;
    const float* src = W + (size_t)k * (CIN * COUT) + (size_t)kbase * COUT + col;
    unsigned int pk[4];
    #pragma unroll
    for (int j = 0; j < 4; ++j) {
        unsigned int lo = f2bf(src[(2 * j) * COUT]);
        unsigned int hi = f2bf(src[(2 * j + 1) * COUT]);
        pk[j] = lo | (hi << 16);
    }
    *reinterpret_cast<uint4*>(wf + (size_t)t * 8) = make_uint4(pk[0], pk[1], pk[2], pk[3]);
}

// feats fp32 [N][64] -> bf16 [N+1][64] (row N = zeros). One thread = 8 elems.
__global__ __launch_bounds__(256) void cvt_feats(const float* __restrict__ f,
                                                 uint4* __restrict__ o, int total8) {
    int t = blockIdx.x * 256 + threadIdx.x;
    if (t < total8) {
        const float4* p = reinterpret_cast<const float4*>(f) + 2 * (size_t)t;
        float4 a = p[0], b = p[1];
        unsigned int u0 = (unsigned int)f2bf(a.x) | ((unsigned int)f2bf(a.y) << 16);
        unsigned int u1 = (unsigned int)f2bf(a.z) | ((unsigned int)f2bf(a.w) << 16);
        unsigned int u2 = (unsigned int)f2bf(b.x) | ((unsigned int)f2bf(b.y) << 16);
        unsigned int u3 = (unsigned int)f2bf(b.z) | ((unsigned int)f2bf(b.w) << 16);
        o[t] = make_uint4(u0, u1, u2, u3);
    } else if (t < total8 + 8) {
        o[t] = make_uint4(0u, 0u, 0u, 0u);   // zero row at index N
    }
}

// Main (round-9 champion, 87.4 us): 4 waves/block, 64 rows/wave. LDS weight
// dbuf, raw s_barrier (lgkmcnt only — counted vmcnt keeps gathers in
// flight), 3-slot A-gather pipeline, idx prefetched 2 iters ahead. Invalid
// pairs gather the zero row (exact zeros).
__global__ __launch_bounds__(256) void spconv_mfma64(
    const char* __restrict__ fbf,          // (n+1) rows x 128 B bf16
    const uint4* __restrict__ wf4,
    const float* __restrict__ bias,
    const int*   __restrict__ in_idx,
    const float* __restrict__ mask,
    float* __restrict__ out, int n)
{
    const int tid  = threadIdx.x;
    const int lane = tid & 63;
    const int wv   = tid >> 6;
    const int rloc = lane & 15;
    const int grp  = lane >> 4;

    // XCD-aware bijective swizzle (neutral, kept)
    const int nwg = gridDim.x;
    int bid = blockIdx.x;
    if ((nwg & 7) == 0) {
        const int chunk = nwg >> 3;
        bid = (blockIdx.x & 7) * chunk + (blockIdx.x >> 3);
    }
    const int row0 = bid * 256 + wv * 64;

    __shared__ uint4 lds_w[2][512];        // double-buffered B-fragments, 16 KB

    f32x4 acc[4][4];
    #pragma unroll
    for (int nt = 0; nt < 4; ++nt) {
        float b = bias[nt * 16 + rloc];
        f32x4 v = {b, b, b, b};
        acc[0][nt] = v; acc[1][nt] = v; acc[2][nt] = v; acc[3][nt] = v;
    }

    int rowt[4];
    #pragma unroll
    for (int t = 0; t < 4; ++t) rowt[t] = row0 + 16 * t + rloc;

    const unsigned zoff = (unsigned)n * 128u;

    // ---- prologue ----
    lds_w[0][tid]       = wf4[tid];
    lds_w[0][tid + 256] = wf4[tid + 256];
    __syncthreads();

    // direct idx/mask for k=0,1; issue their gathers (slots 0,1)
    U4H8 a[3][4][2];
    {
        int i0[4]; float m0[4];
        #pragma unroll
        for (int t = 0; t < 4; ++t) { i0[t] = in_idx[rowt[t]]; m0[t] = mask[rowt[t]]; }
        #pragma unroll
        for (int t = 0; t < 4; ++t) {
            unsigned o = (m0[t] != 0.0f) ? (unsigned)i0[t] * 128u : zoff;
            const uint4* p = reinterpret_cast<const uint4*>(fbf + o) + grp;
            a[0][t][0].u = p[0];
            a[0][t][1].u = p[4];
        }
        #pragma unroll
        for (int t = 0; t < 4; ++t) { i0[t] = in_idx[(size_t)n + rowt[t]]; m0[t] = mask[(size_t)n + rowt[t]]; }
        #pragma unroll
        for (int t = 0; t < 4; ++t) {
            unsigned o = (m0[t] != 0.0f) ? (unsigned)i0[t] * 128u : zoff;
            const uint4* p = reinterpret_cast<const uint4*>(fbf + o) + grp;
            a[1][t][0].u = p[0];
            a[1][t][1].u = p[4];
        }
    }

    // idx(2) -> islot 0, idx(3) -> islot 1
    int idxb[2][4]; float mskb[2][4];
    #pragma unroll
    for (int t = 0; t < 4; ++t) {
        idxb[0][t] = in_idx[(size_t)2 * n + rowt[t]];
        mskb[0][t] = mask[(size_t)2 * n + rowt[t]];
    }
    #pragma unroll
    for (int t = 0; t < 4; ++t) {
        idxb[1][t] = in_idx[(size_t)3 * n + rowt[t]];
        mskb[1][t] = mask[(size_t)3 * n + rowt[t]];
    }

    #pragma unroll
    for (int k = 0; k < KVOL; ++k) {
        const int cur  = k & 1;            // LDS weight buffer for this iter
        const int nxt  = cur ^ 1;
        const int cslot = k % 3;           // A-slot consumed this iter
        const int gslot = (k + 2) % 3;     // A-slot gathered this iter
        const int islot = k & 1;           // idx slot: holds idx(k+2); reload with idx(k+4)

        // 1. weight prefetch for k+1 — oldest vmem ops of the iter, so the
        //    ds_write's counted vmcnt wait leaves younger gathers in flight.
        uint4 w0, w1;
        if (k + 1 < KVOL) {
            const uint4* s = wf4 + (size_t)(k + 1) * 512;
            w0 = s[tid]; w1 = s[tid + 256];
        }

        // 2. A-gathers for k+2 (idx loaded 2 iters ago)
        if (k + 2 < KVOL) {
            #pragma unroll
            for (int t = 0; t < 4; ++t) {
                unsigned o = (mskb[islot][t] != 0.0f) ? (unsigned)idxb[islot][t] * 128u : zoff;
                const uint4* p = reinterpret_cast<const uint4*>(fbf + o) + grp;
                a[gslot][t][0].u = p[0];
                a[gslot][t][1].u = p[4];
            }
        }

        // 3. idx/mask for k+4 into the slot just consumed
        if (k + 4 < KVOL) {
            const size_t kb = (size_t)(k + 4) * n;
            #pragma unroll
            for (int t = 0; t < 4; ++t) {
                idxb[islot][t] = in_idx[kb + rowt[t]];
                mskb[islot][t] = mask[kb + rowt[t]];
            }
        }

        // discourage the scheduler from sinking the gather issue below
        __builtin_amdgcn_sched_barrier(0);

        // 4. B fragments from LDS
        U4H8 bf[2][4];
        #pragma unroll
        for (int kh = 0; kh < 2; ++kh)
            #pragma unroll
            for (int ntl = 0; ntl < 4; ++ntl)
                bf[kh][ntl].u = lds_w[cur][(kh * 4 + ntl) * 64 + lane];

        // 5. 32 MFMAs on fragments gathered 2 iterations ago
        #pragma unroll
        for (int t = 0; t < 4; ++t)
            #pragma unroll
            for (int ntl = 0; ntl < 4; ++ntl) {
                acc[t][ntl] = __builtin_amdgcn_mfma_f32_16x16x32_bf16(a[cslot][t][0].h, bf[0][ntl].h, acc[t][ntl], 0, 0, 0);
                acc[t][ntl] = __builtin_amdgcn_mfma_f32_16x16x32_bf16(a[cslot][t][1].h, bf[1][ntl].h, acc[t][ntl], 0, 0, 0);
            }

        // 6. publish next weight tile; RAW barrier (no vmcnt drain!)
        if (k + 1 < KVOL) {
            lds_w[nxt][tid]       = w0;
            lds_w[nxt][tid + 256] = w1;
            asm volatile("s_waitcnt lgkmcnt(0)" ::: "memory");
            __builtin_amdgcn_s_barrier();
        }
    }

    // C/D layout: col = lane&15, row = grp*4 + reg
    #pragma unroll
    for (int t = 0; t < 4; ++t)
        #pragma unroll
        for (int ntl = 0; ntl < 4; ++ntl)
            #pragma unroll
            for (int r = 0; r < 4; ++r) {
                int orow = row0 + 16 * t + grp * 4 + r;
                out[(size_t)orow * COUT + ntl * 16 + rloc] = acc[t][ntl][r];
            }
}

// ---- fallback (round-2 kernel): fp32 gather + in-loop cvt, used if ws too small ----
static __device__ __forceinline__ bf16x8 cvt8(float4 a, float4 b, float m) {
    bf16x8 r;
    r[0] = (short)f2bf(a.x * m); r[1] = (short)f2bf(a.y * m);
    r[2] = (short)f2bf(a.z * m); r[3] = (short)f2bf(a.w * m);
    r[4] = (short)f2bf(b.x * m); r[5] = (short)f2bf(b.y * m);
    r[6] = (short)f2bf(b.z * m); r[7] = (short)f2bf(b.w * m);
    return r;
}

__global__ __launch_bounds__(256) void spconv_mfma_f32(
    const float* __restrict__ feats,
    const unsigned short* __restrict__ wf,
    const float* __restrict__ bias,
    const int*   __restrict__ in_idx,
    const float* __restrict__ mask,
    float* __restrict__ out, int n)
{
    const int tid  = threadIdx.x;
    const int lane = tid & 63;
    const int wv   = tid >> 6;
    const int rloc = lane & 15;
    const int grp  = lane >> 4;
    const int row0 = blockIdx.x * 128 + wv * 32;

    __shared__ uint4 lds_w[2][512];

    f32x4 acc[2][4];
    #pragma unroll
    for (int nt = 0; nt < 4; ++nt) {
        float b = bias[nt * 16 + rloc];
        f32x4 v = {b, b, b, b};
        acc[0][nt] = v; acc[1][nt] = v;
    }

    const uint4* wf4 = reinterpret_cast<const uint4*>(wf);
    lds_w[0][tid]       = wf4[tid];
    lds_w[0][tid + 256] = wf4[tid + 256];
    __syncthreads();

    const int rowA = row0 + rloc;
    const int rowB = rowA + 16;

    for (int koff = 0; koff < KVOL; ++koff) {
        const int cur = koff & 1;
        uint4 w0, w1;
        const bool pf = (koff + 1 < KVOL);
        if (pf) {
            const uint4* s = wf4 + (size_t)(koff + 1) * 512;
            w0 = s[tid]; w1 = s[tid + 256];
        }

        const size_t kb = (size_t)koff * n;
        const int   idxA = in_idx[kb + rowA];
        const float mA   = mask[kb + rowA];
        const int   idxB = in_idx[kb + rowB];
        const float mB   = mask[kb + rowB];

        const float4* fA = reinterpret_cast<const float4*>(feats + (size_t)idxA * CIN + grp * 8);
        const float4* fB = reinterpret_cast<const float4*>(feats + (size_t)idxB * CIN + grp * 8);
        float4 a0 = fA[0], a1 = fA[1], a2 = fA[8], a3 = fA[9];
        float4 c0 = fB[0], c1 = fB[1], c2 = fB[8], c3 = fB[9];

        bf16x8 aA0 = cvt8(a0, a1, mA), aA1 = cvt8(a2, a3, mA);
        bf16x8 aB0 = cvt8(c0, c1, mB), aB1 = cvt8(c2, c3, mB);

        U4H8 bf[2][4];
        #pragma unroll
        for (int kh = 0; kh < 2; ++kh)
            #pragma unroll
            for (int nt = 0; nt < 4; ++nt)
                bf[kh][nt].u = lds_w[cur][(kh * 4 + nt) * 64 + lane];

        #pragma unroll
        for (int nt = 0; nt < 4; ++nt) {
            acc[0][nt] = __builtin_amdgcn_mfma_f32_16x16x32_bf16(aA0, bf[0][nt].h, acc[0][nt], 0, 0, 0);
            acc[0][nt] = __builtin_amdgcn_mfma_f32_16x16x32_bf16(aA1, bf[1][nt].h, acc[0][nt], 0, 0, 0);
            acc[1][nt] = __builtin_amdgcn_mfma_f32_16x16x32_bf16(aB0, bf[0][nt].h, acc[1][nt], 0, 0, 0);
            acc[1][nt] = __builtin_amdgcn_mfma_f32_16x16x32_bf16(aB1, bf[1][nt].h, acc[1][nt], 0, 0, 0);
        }

        if (pf) {
            lds_w[cur ^ 1][tid]       = w0;
            lds_w[cur ^ 1][tid + 256] = w1;
        }
        __syncthreads();
    }

    #pragma unroll
    for (int t = 0; t < 2; ++t)
        #pragma unroll
        for (int nt = 0; nt < 4; ++nt)
            #pragma unroll
            for (int r = 0; r < 4; ++r) {
                int orow = row0 + t * 16 + grp * 4 + r;
                out[(size_t)orow * COUT + nt * 16 + rloc] = acc[t][nt][r];
            }
}

extern "C" void kernel_launch(void* const* d_in, const int* in_sizes, int n_in,
                              void* d_out, int out_size, void* d_ws, size_t ws_size,
                              hipStream_t stream)
{
    const float* feats  = (const float*)d_in[0];
    const float* weight = (const float*)d_in[1];
    const float* bias   = (const float*)d_in[2];
    const int*   in_idx = (const int*)  d_in[3];
    // d_in[4] = out_idx (unused: out_idx[k][i] == i where mask==1)
    const float* mask   = (const float*)d_in[5];
    float* out = (float*)d_out;

    const int n = in_sizes[0] / CIN;  // 262144

    const size_t WF_BYTES  = (size_t)KVOL * 8 * 64 * 16;          // 221184
    const size_t FBF_BYTES = (size_t)(n + 1) * CIN * 2;           // ~33.6 MB

    unsigned short* wf = (unsigned short*)d_ws;
    const int packN = KVOL * 8 * 64;
    pack_w<<<(packN + 255) / 256, 256, 0, stream>>>(weight, wf);

    if (ws_size >= WF_BYTES + FBF_BYTES) {
        char* fbf = (char*)d_ws + WF_BYTES;
        const int total8 = n * 8;                                  // uint4s of feats
        cvt_feats<<<(total8 + 8 + 255) / 256, 256, 0, stream>>>(feats, (uint4*)fbf, total8);
        spconv_mfma64<<<n / 256, 256, 0, stream>>>(fbf, (const uint4*)wf, bias,
                                                   in_idx, mask, out, n);
    } else {
        spconv_mfma_f32<<<n / 128, 256, 0, stream>>>(feats, wf, bias,
                                                     in_idx, mask, out, n);
    }
}